// Round 3
// baseline (4210.505 us; speedup 1.0000x reference)
//
#include <hip/hip_runtime.h>

#define S_LEN 4096
#define BATCH 4
#define NROWS 16384   // S*B
#define DIM   1024
#define DEPTH 8       // scan prefetch depth

typedef __attribute__((ext_vector_type(8))) short short8;
typedef __attribute__((ext_vector_type(4))) float floatx4;
typedef _Float16 half_t;
typedef __attribute__((ext_vector_type(8))) _Float16 half8;

__device__ __forceinline__ float bf2f(short s) {
    union { unsigned int u; float f; } c;
    c.u = ((unsigned int)(unsigned short)s) << 16;
    return c.f;
}
__device__ __forceinline__ short f2bf(float f) {
    union { float f; unsigned int u; } c; c.f = f;
    unsigned int r = c.u + 0x7fffu + ((c.u >> 16) & 1u);
    return (short)(r >> 16);
}
// split fp32 -> bf16 hi + bf16 lo (a ~= hi + lo, rel err ~2^-16)
__device__ __forceinline__ void split_bf16(float x, short& hi, short& lo) {
    short h = f2bf(x);
    hi = h;
    lo = f2bf(x - bf2f(h));
}

// W[K][N] fp32 row-major -> Wt[N][K]
__global__ __launch_bounds__(256) void transpose_k(const float* __restrict__ W,
                                                   float* __restrict__ Wt,
                                                   int K, int N) {
    int idx = blockIdx.x * 256 + threadIdx.x;
    if (idx >= N * K) return;
    int n = idx / K;
    int k = idx - n * K;
    Wt[idx] = W[k * N + n];
}

// C = A[M,K] @ Bt[N,K]^T. A fp32 or fp16, Bt fp32. Split-bf16 3-term MFMA, fp32 acc.
// MODE 0: fp32 out at row*N+col (+ optional fp32 bias)
// MODE 1: fp16 out at row*2048 + (col>>6)*128 + (col&63)   (dpfp staging layout)
template <typename AT, int MODE>
__global__ __launch_bounds__(256) void gemm_bt(const AT* __restrict__ A,
                                               const float* __restrict__ Bt,
                                               void* __restrict__ Cout,
                                               const float* __restrict__ bias,
                                               int N, int K) {
    __shared__ __align__(16) short As_h[64][40], As_l[64][40];
    __shared__ __align__(16) short Bs_h[64][40], Bs_l[64][40];
    const int tid  = threadIdx.x;
    const int wave = tid >> 6, lane = tid & 63;
    const int row0 = blockIdx.x * 64, col0 = blockIdx.y * 64;
    const int lr = tid >> 2, lc = (tid & 3) * 8;   // staging: 64 rows x 4 groups of 8
    const AT*    Ap = A  + (size_t)(row0 + lr) * K + lc;
    const float* Bp = Bt + (size_t)(col0 + lr) * K + lc;
    const int am = wave * 16 + (lane & 15);        // A-frag row
    const int ak = (lane >> 4) * 8;                // k-slice start
    floatx4 acc[4];
    #pragma unroll
    for (int t = 0; t < 4; ++t) acc[t] = (floatx4){0.f, 0.f, 0.f, 0.f};

    for (int k0 = 0; k0 < K; k0 += 32) {
        float av[8], bv[8];
        if constexpr (sizeof(AT) == 4) {
            floatx4 a0 = *(const floatx4*)(Ap + k0);
            floatx4 a1 = *(const floatx4*)(Ap + k0 + 4);
            #pragma unroll
            for (int j = 0; j < 4; ++j) { av[j] = a0[j]; av[4 + j] = a1[j]; }
        } else {
            half8 a = *(const half8*)(Ap + k0);
            #pragma unroll
            for (int j = 0; j < 8; ++j) av[j] = (float)a[j];
        }
        floatx4 b0 = *(const floatx4*)(Bp + k0);
        floatx4 b1 = *(const floatx4*)(Bp + k0 + 4);
        #pragma unroll
        for (int j = 0; j < 4; ++j) { bv[j] = b0[j]; bv[4 + j] = b1[j]; }

        short8 ah, al, bh, bl;
        #pragma unroll
        for (int j = 0; j < 8; ++j) {
            short h, l;
            split_bf16(av[j], h, l); ah[j] = h; al[j] = l;
            split_bf16(bv[j], h, l); bh[j] = h; bl[j] = l;
        }
        *(short8*)&As_h[lr][lc] = ah;
        *(short8*)&As_l[lr][lc] = al;
        *(short8*)&Bs_h[lr][lc] = bh;
        *(short8*)&Bs_l[lr][lc] = bl;
        __syncthreads();
        short8 afh = *(const short8*)&As_h[am][ak];
        short8 afl = *(const short8*)&As_l[am][ak];
        #pragma unroll
        for (int t = 0; t < 4; ++t) {
            short8 bfh = *(const short8*)&Bs_h[t * 16 + (lane & 15)][ak];
            short8 bfl = *(const short8*)&Bs_l[t * 16 + (lane & 15)][ak];
            acc[t] = __builtin_amdgcn_mfma_f32_16x16x32_bf16(afh, bfh, acc[t], 0, 0, 0);
            acc[t] = __builtin_amdgcn_mfma_f32_16x16x32_bf16(afh, bfl, acc[t], 0, 0, 0);
            acc[t] = __builtin_amdgcn_mfma_f32_16x16x32_bf16(afl, bfh, acc[t], 0, 0, 0);
        }
        __syncthreads();
    }
    // C/D layout (verified m89/m91): col = lane&15, row = (lane>>4)*4 + reg
    const int crow = row0 + wave * 16 + (lane >> 4) * 4;
    const int ccol = lane & 15;
    #pragma unroll
    for (int t = 0; t < 4; ++t) {
        int col = col0 + t * 16 + ccol;
        #pragma unroll
        for (int r = 0; r < 4; ++r) {
            int row = crow + r;
            float v = acc[t][r];
            if (MODE == 0) {
                float b = bias ? bias[col] : 0.f;
                ((float*)Cout)[(size_t)row * N + col] = v + b;
            } else {
                ((half_t*)Cout)[(size_t)row * 2048 + (col >> 6) * 128 + (col & 63)] = (half_t)v;
            }
        }
    }
}

// beta = sigmoid(x @ Wb); one wave per row, Wbt fp32 [16][1024]
__global__ __launch_bounds__(256) void beta_kernel(const float* __restrict__ X,
                                                   const float* __restrict__ Wbt,
                                                   float* __restrict__ Beta) {
    int wid  = (blockIdx.x * 256 + threadIdx.x) >> 6;
    int lane = threadIdx.x & 63;
    if (wid >= NROWS) return;
    const float* xr = X + (size_t)wid * DIM + lane * 16;
    float xv[16];
    #pragma unroll
    for (int j = 0; j < 4; ++j) {
        floatx4 v = *(const floatx4*)(xr + j * 4);
        #pragma unroll
        for (int e = 0; e < 4; ++e) xv[j * 4 + e] = v[e];
    }
    #pragma unroll 1
    for (int h = 0; h < 16; ++h) {
        const float* wr = Wbt + h * DIM + lane * 16;
        float s = 0.f;
        #pragma unroll
        for (int j = 0; j < 4; ++j) {
            floatx4 v = *(const floatx4*)(wr + j * 4);
            #pragma unroll
            for (int e = 0; e < 4; ++e) s = fmaf(xv[j * 4 + e], v[e], s);
        }
        #pragma unroll
        for (int off = 32; off; off >>= 1) s += __shfl_xor(s, off);
        if (lane == 0) Beta[wid * 16 + h] = 1.f / (1.f + __expf(-s));
    }
}

// In-place DPFP on fp16 spans of 128 (first 64 hold raw p, written by gemm MODE 1).
// xc = relu([p,-p]) (len 128), phi[j] = xc[j]*xc[(j-1) mod 128], normalized by (sum+1e-6).
__global__ __launch_bounds__(256) void dpfp_h(half_t* __restrict__ P) {
    int gw   = (blockIdx.x * 256 + threadIdx.x) >> 6;
    int lane = threadIdx.x & 63;
    half_t* base = P + (size_t)gw * 128;
    float p  = (float)base[lane];
    float pm = __shfl(p, (lane + 63) & 63);           // p[lane-1], lane0 gets p[63]
    float rp  = fmaxf(p, 0.f),  rn  = fmaxf(-p, 0.f);
    float rpm = fmaxf(pm, 0.f), rnm = fmaxf(-pm, 0.f);
    float aprev = (lane == 0) ? rnm : rpm;            // xc[(lane-1)%128]
    float bprev = (lane == 0) ? rpm : rnm;            // xc[lane+63]
    float phi_a = rp * aprev;                         // phi[lane]
    float phi_b = rn * bprev;                         // phi[lane+64]
    float s = phi_a + phi_b;
    #pragma unroll
    for (int off = 32; off; off >>= 1) s += __shfl_xor(s, off);
    float inv = 1.f / (s + 1e-6f);
    base[lane]      = (half_t)(phi_a * inv);
    base[64 + lane] = (half_t)(phi_b * inv);
}

__device__ __forceinline__ void load8h(const half_t* p, float* d) {
    half8 v = *(const half8*)p;
    #pragma unroll
    for (int j = 0; j < 8; ++j) d[j] = (float)v[j];
}

// Sequential fast-weight scan: w <- w + beta*(v - w.k)*k ; y = w.q
// Block = one (b,h) x 16 state rows; 16 lanes/row x 8 fp32 state each.
__global__ __launch_bounds__(256) void scan_kernel(const half_t* __restrict__ PhiK,
                                                   const half_t* __restrict__ PhiQ,
                                                   const float* __restrict__ V,
                                                   const float* __restrict__ Beta,
                                                   half_t* __restrict__ Y) {
    const int bh = blockIdx.x >> 2;     // 0..63
    const int rc = blockIdx.x & 3;      // row chunk
    const int b = bh >> 4, h = bh & 15;
    const int row_l = threadIdx.x >> 4; // 0..15
    const int tc = threadIdx.x & 15;    // column group (8 values)
    const int vrow = rc * 16 + row_l;   // 0..63
    const half_t* kbase = PhiK + h * 128 + tc * 8;
    const half_t* qbase = PhiQ + h * 128 + tc * 8;
    const float*  vbase = V + h * 64 + vrow;
    const float*  bbase = Beta + h;
    half_t* ybase = Y + h * 64 + vrow;

    float w[8];
    #pragma unroll
    for (int j = 0; j < 8; ++j) w[j] = 0.f;

    float kb[DEPTH][8], qb[DEPTH][8], vb[DEPTH], be[DEPTH];
    #pragma unroll
    for (int u = 0; u < DEPTH; ++u) {
        size_t r = (size_t)(u * BATCH + b);
        load8h(kbase + r * 2048, kb[u]);
        load8h(qbase + r * 2048, qb[u]);
        vb[u] = vbase[r * 1024];
        be[u] = bbase[r * 16];
    }

    for (int s = 0; s < S_LEN; s += DEPTH) {
        #pragma unroll
        for (int u = 0; u < DEPTH; ++u) {
            float d0 = w[0] * kb[u][0];
            float d1 = w[1] * kb[u][1];
            d0 = fmaf(w[2], kb[u][2], d0); d1 = fmaf(w[3], kb[u][3], d1);
            d0 = fmaf(w[4], kb[u][4], d0); d1 = fmaf(w[5], kb[u][5], d1);
            d0 = fmaf(w[6], kb[u][6], d0); d1 = fmaf(w[7], kb[u][7], d1);
            float d = d0 + d1;
            d += __shfl_xor(d, 1);
            d += __shfl_xor(d, 2);
            d += __shfl_xor(d, 4);
            d += __shfl_xor(d, 8);
            float c = be[u] * (vb[u] - d);
            #pragma unroll
            for (int j = 0; j < 8; ++j) w[j] = fmaf(c, kb[u][j], w[j]);
            float y0 = w[0] * qb[u][0];
            float y1 = w[1] * qb[u][1];
            y0 = fmaf(w[2], qb[u][2], y0); y1 = fmaf(w[3], qb[u][3], y1);
            y0 = fmaf(w[4], qb[u][4], y0); y1 = fmaf(w[5], qb[u][5], y1);
            y0 = fmaf(w[6], qb[u][6], y0); y1 = fmaf(w[7], qb[u][7], y1);
            float y = y0 + y1;
            y += __shfl_xor(y, 1);
            y += __shfl_xor(y, 2);
            y += __shfl_xor(y, 4);
            y += __shfl_xor(y, 8);
            if (tc == 0) ybase[(size_t)((s + u) * BATCH + b) * 1024] = (half_t)y;
            int sn = s + u + DEPTH;
            if (sn < S_LEN) {  // uniform branch; refill ring slot u
                size_t r = (size_t)(sn * BATCH + b);
                load8h(kbase + r * 2048, kb[u]);
                load8h(qbase + r * 2048, qb[u]);
                vb[u] = vbase[r * 1024];
                be[u] = bbase[r * 16];
            }
        }
    }
}

extern "C" void kernel_launch(void* const* d_in, const int* in_sizes, int n_in,
                              void* d_out, int out_size, void* d_ws, size_t ws_size,
                              hipStream_t stream) {
    const float* x  = (const float*)d_in[0];
    const float* Wq = (const float*)d_in[1];
    const float* Wk = (const float*)d_in[2];
    const float* Wv = (const float*)d_in[3];
    const float* Wb = (const float*)d_in[4];
    const float* Wo = (const float*)d_in[5];
    const float* bo = (const float*)d_in[6];

    char* ws = (char*)d_ws;
    size_t off = 0;
    auto alloc = [&](size_t bytes) -> void* {
        void* p = ws + off;
        off += (bytes + 255) & ~(size_t)255;
        return p;
    };
    half_t* PhiQ = (half_t*)alloc((size_t)NROWS * 2048 * 2);  // 64 MB
    half_t* PhiK = (half_t*)alloc((size_t)NROWS * 2048 * 2);  // 64 MB
    half_t* Yb   = (half_t*)alloc((size_t)NROWS * 1024 * 2);  // 32 MB
    float*  Beta = (float*)alloc((size_t)NROWS * 16 * 4);     //  1 MB
    float*  Wqt  = (float*)alloc((size_t)1024 * 1024 * 4);    //  4 MB
    float*  Wkt  = (float*)alloc((size_t)1024 * 1024 * 4);
    float*  Wvt  = (float*)alloc((size_t)1024 * 1024 * 4);
    float*  Wot  = (float*)alloc((size_t)1024 * 1024 * 4);
    float*  Wbt  = (float*)alloc((size_t)16 * 1024 * 4);
    float*  Vb   = (float*)d_out;  // V staged in d_out (fp32, dead before final GEMM)

    transpose_k<<<4096, 256, 0, stream>>>(Wq, Wqt, 1024, 1024);
    transpose_k<<<4096, 256, 0, stream>>>(Wk, Wkt, 1024, 1024);
    transpose_k<<<4096, 256, 0, stream>>>(Wv, Wvt, 1024, 1024);
    transpose_k<<<4096, 256, 0, stream>>>(Wo, Wot, 1024, 1024);
    transpose_k<<<64,   256, 0, stream>>>(Wb, Wbt, 1024, 16);

    dim3 ggrid(NROWS / 64, DIM / 64);
    const int dgrid = (NROWS * 16) / 4;
    gemm_bt<float, 1><<<ggrid, 256, 0, stream>>>(x, Wqt, PhiQ, nullptr, DIM, DIM);
    dpfp_h<<<dgrid, 256, 0, stream>>>(PhiQ);
    gemm_bt<float, 1><<<ggrid, 256, 0, stream>>>(x, Wkt, PhiK, nullptr, DIM, DIM);
    dpfp_h<<<dgrid, 256, 0, stream>>>(PhiK);
    gemm_bt<float, 0><<<ggrid, 256, 0, stream>>>(x, Wvt, Vb, nullptr, DIM, DIM);
    beta_kernel<<<NROWS / 4, 256, 0, stream>>>(x, Wbt, Beta);
    scan_kernel<<<256, 256, 0, stream>>>(PhiK, PhiQ, Vb, Beta, Yb);
    gemm_bt<half_t, 0><<<ggrid, 256, 0, stream>>>(Yb, Wot, d_out, bo, DIM, DIM);
}

// Round 5
// 3379.289 us; speedup vs baseline: 1.2460x; 1.2460x over previous
//
#include <hip/hip_runtime.h>

#define S_LEN 4096
#define BATCH 4
#define NROWS 16384   // S*B
#define DIM   1024
#define DEPTH 8       // scan prefetch depth

typedef __attribute__((ext_vector_type(8))) short short8;
typedef __attribute__((ext_vector_type(4))) float floatx4;
typedef _Float16 half_t;
typedef __attribute__((ext_vector_type(8))) _Float16 half8;

__device__ __forceinline__ float bf2f(short s) {
    union { unsigned int u; float f; } c;
    c.u = ((unsigned int)(unsigned short)s) << 16;
    return c.f;
}
__device__ __forceinline__ short f2bf(float f) {
    union { float f; unsigned int u; } c; c.f = f;
    unsigned int r = c.u + 0x7fffu + ((c.u >> 16) & 1u);
    return (short)(r >> 16);
}
// split fp32 -> bf16 hi + bf16 lo (a ~= hi + lo, rel err ~2^-16)
__device__ __forceinline__ void split_bf16(float x, short& hi, short& lo) {
    short h = f2bf(x);
    hi = h;
    lo = f2bf(x - bf2f(h));
}

// 16-lane (DPP row) all-reduce sum: quad_perm xor1, xor2, row_ror:4, row_ror:8.
// ~8 cyc per stage vs ~130 cyc per ds_bpermute-based __shfl_xor.
__device__ __forceinline__ float row16_allreduce(float x) {
    union fi { float f; int i; };
    fi a, b;
    a.f = x;
    b.i = __builtin_amdgcn_update_dpp(0, a.i, 0xB1,  0xF, 0xF, true); a.f += b.f; // xor1
    b.i = __builtin_amdgcn_update_dpp(0, a.i, 0x4E,  0xF, 0xF, true); a.f += b.f; // xor2
    b.i = __builtin_amdgcn_update_dpp(0, a.i, 0x124, 0xF, 0xF, true); a.f += b.f; // ror4
    b.i = __builtin_amdgcn_update_dpp(0, a.i, 0x128, 0xF, 0xF, true); a.f += b.f; // ror8
    return a.f;
}

// W[K][N] fp32 row-major -> Wt[N][K]
__global__ __launch_bounds__(256) void transpose_k(const float* __restrict__ W,
                                                   float* __restrict__ Wt,
                                                   int K, int N) {
    int idx = blockIdx.x * 256 + threadIdx.x;
    if (idx >= N * K) return;
    int n = idx / K;
    int k = idx - n * K;
    Wt[idx] = W[k * N + n];
}

// C = A[M,K] @ Bt[N,K]^T. A fp32 or fp16, Bt fp32. Split-bf16 3-term MFMA, fp32 acc.
// MODE 0: fp32 out at row*N+col (+ optional fp32 bias)
// MODE 1: fp16 out at row*2048 + (col>>6)*128 + (col&63)   (dpfp staging layout)
template <typename AT, int MODE>
__global__ __launch_bounds__(256) void gemm_bt(const AT* __restrict__ A,
                                               const float* __restrict__ Bt,
                                               void* __restrict__ Cout,
                                               const float* __restrict__ bias,
                                               int N, int K) {
    __shared__ __align__(16) short As_h[64][40], As_l[64][40];
    __shared__ __align__(16) short Bs_h[64][40], Bs_l[64][40];
    const int tid  = threadIdx.x;
    const int wave = tid >> 6, lane = tid & 63;
    const int row0 = blockIdx.x * 64, col0 = blockIdx.y * 64;
    const int lr = tid >> 2, lc = (tid & 3) * 8;   // staging: 64 rows x 4 groups of 8
    const AT*    Ap = A  + (size_t)(row0 + lr) * K + lc;
    const float* Bp = Bt + (size_t)(col0 + lr) * K + lc;
    const int am = wave * 16 + (lane & 15);        // A-frag row
    const int ak = (lane >> 4) * 8;                // k-slice start
    floatx4 acc[4];
    #pragma unroll
    for (int t = 0; t < 4; ++t) acc[t] = (floatx4){0.f, 0.f, 0.f, 0.f};

    for (int k0 = 0; k0 < K; k0 += 32) {
        float av[8], bv[8];
        if constexpr (sizeof(AT) == 4) {
            floatx4 a0 = *(const floatx4*)(Ap + k0);
            floatx4 a1 = *(const floatx4*)(Ap + k0 + 4);
            #pragma unroll
            for (int j = 0; j < 4; ++j) { av[j] = a0[j]; av[4 + j] = a1[j]; }
        } else {
            half8 a = *(const half8*)(Ap + k0);
            #pragma unroll
            for (int j = 0; j < 8; ++j) av[j] = (float)a[j];
        }
        floatx4 b0 = *(const floatx4*)(Bp + k0);
        floatx4 b1 = *(const floatx4*)(Bp + k0 + 4);
        #pragma unroll
        for (int j = 0; j < 4; ++j) { bv[j] = b0[j]; bv[4 + j] = b1[j]; }

        short8 ah, al, bh, bl;
        #pragma unroll
        for (int j = 0; j < 8; ++j) {
            short h, l;
            split_bf16(av[j], h, l); ah[j] = h; al[j] = l;
            split_bf16(bv[j], h, l); bh[j] = h; bl[j] = l;
        }
        *(short8*)&As_h[lr][lc] = ah;
        *(short8*)&As_l[lr][lc] = al;
        *(short8*)&Bs_h[lr][lc] = bh;
        *(short8*)&Bs_l[lr][lc] = bl;
        __syncthreads();
        short8 afh = *(const short8*)&As_h[am][ak];
        short8 afl = *(const short8*)&As_l[am][ak];
        #pragma unroll
        for (int t = 0; t < 4; ++t) {
            short8 bfh = *(const short8*)&Bs_h[t * 16 + (lane & 15)][ak];
            short8 bfl = *(const short8*)&Bs_l[t * 16 + (lane & 15)][ak];
            acc[t] = __builtin_amdgcn_mfma_f32_16x16x32_bf16(afh, bfh, acc[t], 0, 0, 0);
            acc[t] = __builtin_amdgcn_mfma_f32_16x16x32_bf16(afh, bfl, acc[t], 0, 0, 0);
            acc[t] = __builtin_amdgcn_mfma_f32_16x16x32_bf16(afl, bfh, acc[t], 0, 0, 0);
        }
        __syncthreads();
    }
    // C/D layout (verified m89/m91): col = lane&15, row = (lane>>4)*4 + reg
    const int crow = row0 + wave * 16 + (lane >> 4) * 4;
    const int ccol = lane & 15;
    #pragma unroll
    for (int t = 0; t < 4; ++t) {
        int col = col0 + t * 16 + ccol;
        #pragma unroll
        for (int r = 0; r < 4; ++r) {
            int row = crow + r;
            float v = acc[t][r];
            if (MODE == 0) {
                float b = bias ? bias[col] : 0.f;
                ((float*)Cout)[(size_t)row * N + col] = v + b;
            } else {
                ((half_t*)Cout)[(size_t)row * 2048 + (col >> 6) * 128 + (col & 63)] = (half_t)v;
            }
        }
    }
}

// beta = sigmoid(x @ Wb); one wave per row, Wbt fp32 [16][1024]
__global__ __launch_bounds__(256) void beta_kernel(const float* __restrict__ X,
                                                   const float* __restrict__ Wbt,
                                                   float* __restrict__ Beta) {
    int wid  = (blockIdx.x * 256 + threadIdx.x) >> 6;
    int lane = threadIdx.x & 63;
    if (wid >= NROWS) return;
    const float* xr = X + (size_t)wid * DIM + lane * 16;
    float xv[16];
    #pragma unroll
    for (int j = 0; j < 4; ++j) {
        floatx4 v = *(const floatx4*)(xr + j * 4);
        #pragma unroll
        for (int e = 0; e < 4; ++e) xv[j * 4 + e] = v[e];
    }
    #pragma unroll 1
    for (int h = 0; h < 16; ++h) {
        const float* wr = Wbt + h * DIM + lane * 16;
        float s = 0.f;
        #pragma unroll
        for (int j = 0; j < 4; ++j) {
            floatx4 v = *(const floatx4*)(wr + j * 4);
            #pragma unroll
            for (int e = 0; e < 4; ++e) s = fmaf(xv[j * 4 + e], v[e], s);
        }
        #pragma unroll
        for (int off = 32; off; off >>= 1) s += __shfl_xor(s, off);
        if (lane == 0) Beta[wid * 16 + h] = 1.f / (1.f + __expf(-s));
    }
}

// In-place DPFP on fp16 spans of 128 (first 64 hold raw p, written by gemm MODE 1).
// xc = relu([p,-p]) (len 128), phi[j] = xc[j]*xc[(j-1) mod 128], normalized by (sum+1e-6).
__global__ __launch_bounds__(256) void dpfp_h(half_t* __restrict__ P) {
    int gw   = (blockIdx.x * 256 + threadIdx.x) >> 6;
    int lane = threadIdx.x & 63;
    half_t* base = P + (size_t)gw * 128;
    float p  = (float)base[lane];
    float pm = __shfl(p, (lane + 63) & 63);           // p[lane-1], lane0 gets p[63]
    float rp  = fmaxf(p, 0.f),  rn  = fmaxf(-p, 0.f);
    float rpm = fmaxf(pm, 0.f), rnm = fmaxf(-pm, 0.f);
    float aprev = (lane == 0) ? rnm : rpm;            // xc[(lane-1)%128]
    float bprev = (lane == 0) ? rpm : rnm;            // xc[lane+63]
    float phi_a = rp * aprev;                         // phi[lane]
    float phi_b = rn * bprev;                         // phi[lane+64]
    float s = phi_a + phi_b;
    #pragma unroll
    for (int off = 32; off; off >>= 1) s += __shfl_xor(s, off);
    float inv = 1.f / (s + 1e-6f);
    base[lane]      = (half_t)(phi_a * inv);
    base[64 + lane] = (half_t)(phi_b * inv);
}

__device__ __forceinline__ void load8h(const half_t* p, float* d) {
    half8 v = *(const half8*)p;
    #pragma unroll
    for (int j = 0; j < 8; ++j) d[j] = (float)v[j];
}

// Sequential fast-weight scan: w <- w + beta*(v - w.k)*k ; y = w.q
// Block = one (b,h) x 16 state rows; 16 lanes/row x 8 fp32 state each.
// Reductions via DPP row ops (no LDS/ds_bpermute on the critical path).
__global__ __launch_bounds__(256, 1) void scan_kernel(const half_t* __restrict__ PhiK,
                                                      const half_t* __restrict__ PhiQ,
                                                      const float* __restrict__ V,
                                                      const float* __restrict__ Beta,
                                                      half_t* __restrict__ Y) {
    const int bh = blockIdx.x >> 2;     // 0..63
    const int rc = blockIdx.x & 3;      // row chunk
    const int b = bh >> 4, h = bh & 15;
    const int row_l = threadIdx.x >> 4; // 0..15
    const int tc = threadIdx.x & 15;    // column group (8 values)
    const int vrow = rc * 16 + row_l;   // 0..63
    const half_t* kbase = PhiK + h * 128 + tc * 8;
    const half_t* qbase = PhiQ + h * 128 + tc * 8;
    const float*  vbase = V + h * 64 + vrow;
    const float*  bbase = Beta + h;
    half_t* ybase = Y + h * 64 + vrow;

    float w[8];
    #pragma unroll
    for (int j = 0; j < 8; ++j) w[j] = 0.f;

    float kb[DEPTH][8], qb[DEPTH][8], vb[DEPTH], be[DEPTH];
    #pragma unroll
    for (int u = 0; u < DEPTH; ++u) {
        size_t r = (size_t)(u * BATCH + b);
        load8h(kbase + r * 2048, kb[u]);
        load8h(qbase + r * 2048, qb[u]);
        vb[u] = vbase[r * 1024];
        be[u] = bbase[r * 16];
    }

    for (int s = 0; s < S_LEN; s += DEPTH) {
        #pragma unroll
        for (int u = 0; u < DEPTH; ++u) {
            float d0 = w[0] * kb[u][0];
            float d1 = w[1] * kb[u][1];
            d0 = fmaf(w[2], kb[u][2], d0); d1 = fmaf(w[3], kb[u][3], d1);
            d0 = fmaf(w[4], kb[u][4], d0); d1 = fmaf(w[5], kb[u][5], d1);
            d0 = fmaf(w[6], kb[u][6], d0); d1 = fmaf(w[7], kb[u][7], d1);
            float d = row16_allreduce(d0 + d1);
            float c = be[u] * (vb[u] - d);
            #pragma unroll
            for (int j = 0; j < 8; ++j) w[j] = fmaf(c, kb[u][j], w[j]);
            float y0 = w[0] * qb[u][0];
            float y1 = w[1] * qb[u][1];
            y0 = fmaf(w[2], qb[u][2], y0); y1 = fmaf(w[3], qb[u][3], y1);
            y0 = fmaf(w[4], qb[u][4], y0); y1 = fmaf(w[5], qb[u][5], y1);
            y0 = fmaf(w[6], qb[u][6], y0); y1 = fmaf(w[7], qb[u][7], y1);
            float y = row16_allreduce(y0 + y1);
            if (tc == 0) ybase[(size_t)((s + u) * BATCH + b) * 1024] = (half_t)y;
            int sn = s + u + DEPTH;
            if (sn < S_LEN) {  // uniform branch; refill ring slot u
                size_t r = (size_t)(sn * BATCH + b);
                load8h(kbase + r * 2048, kb[u]);
                load8h(qbase + r * 2048, qb[u]);
                vb[u] = vbase[r * 1024];
                be[u] = bbase[r * 16];
            }
        }
    }
}

extern "C" void kernel_launch(void* const* d_in, const int* in_sizes, int n_in,
                              void* d_out, int out_size, void* d_ws, size_t ws_size,
                              hipStream_t stream) {
    const float* x  = (const float*)d_in[0];
    const float* Wq = (const float*)d_in[1];
    const float* Wk = (const float*)d_in[2];
    const float* Wv = (const float*)d_in[3];
    const float* Wb = (const float*)d_in[4];
    const float* Wo = (const float*)d_in[5];
    const float* bo = (const float*)d_in[6];

    char* ws = (char*)d_ws;
    size_t off = 0;
    auto alloc = [&](size_t bytes) -> void* {
        void* p = ws + off;
        off += (bytes + 255) & ~(size_t)255;
        return p;
    };
    half_t* PhiQ = (half_t*)alloc((size_t)NROWS * 2048 * 2);  // 64 MB
    half_t* PhiK = (half_t*)alloc((size_t)NROWS * 2048 * 2);  // 64 MB
    half_t* Yb   = (half_t*)alloc((size_t)NROWS * 1024 * 2);  // 32 MB
    float*  Beta = (float*)alloc((size_t)NROWS * 16 * 4);     //  1 MB
    float*  Wqt  = (float*)alloc((size_t)1024 * 1024 * 4);    //  4 MB
    float*  Wkt  = (float*)alloc((size_t)1024 * 1024 * 4);
    float*  Wvt  = (float*)alloc((size_t)1024 * 1024 * 4);
    float*  Wot  = (float*)alloc((size_t)1024 * 1024 * 4);
    float*  Wbt  = (float*)alloc((size_t)16 * 1024 * 4);
    float*  Vb   = (float*)d_out;  // V staged in d_out (fp32, dead before final GEMM)

    transpose_k<<<4096, 256, 0, stream>>>(Wq, Wqt, 1024, 1024);
    transpose_k<<<4096, 256, 0, stream>>>(Wk, Wkt, 1024, 1024);
    transpose_k<<<4096, 256, 0, stream>>>(Wv, Wvt, 1024, 1024);
    transpose_k<<<4096, 256, 0, stream>>>(Wo, Wot, 1024, 1024);
    transpose_k<<<64,   256, 0, stream>>>(Wb, Wbt, 1024, 16);

    dim3 ggrid(NROWS / 64, DIM / 64);
    const int dgrid = (NROWS * 16) / 4;
    gemm_bt<float, 1><<<ggrid, 256, 0, stream>>>(x, Wqt, PhiQ, nullptr, DIM, DIM);
    dpfp_h<<<dgrid, 256, 0, stream>>>(PhiQ);
    gemm_bt<float, 1><<<ggrid, 256, 0, stream>>>(x, Wkt, PhiK, nullptr, DIM, DIM);
    dpfp_h<<<dgrid, 256, 0, stream>>>(PhiK);
    gemm_bt<float, 0><<<ggrid, 256, 0, stream>>>(x, Wvt, Vb, nullptr, DIM, DIM);
    beta_kernel<<<NROWS / 4, 256, 0, stream>>>(x, Wbt, Beta);
    scan_kernel<<<256, 256, 0, stream>>>(PhiK, PhiQ, Vb, Beta, Yb);
    gemm_bt<half_t, 0><<<ggrid, 256, 0, stream>>>(Yb, Wot, d_out, bo, DIM, DIM);
}

// Round 6
// 1705.512 us; speedup vs baseline: 2.4688x; 1.9814x over previous
//
#include <hip/hip_runtime.h>

#define S_LEN 4096
#define BATCH 4
#define NROWS 16384   // S*B
#define DIM   1024
#define CHUNK 32
#define NCHUNK (S_LEN / CHUNK)

typedef __attribute__((ext_vector_type(8))) short short8;
typedef __attribute__((ext_vector_type(4))) float floatx4;
typedef _Float16 half_t;
typedef __attribute__((ext_vector_type(8))) _Float16 half8;

__device__ __forceinline__ float bf2f(short s) {
    union { unsigned int u; float f; } c;
    c.u = ((unsigned int)(unsigned short)s) << 16;
    return c.f;
}
__device__ __forceinline__ short f2bf(float f) {
    union { float f; unsigned int u; } c; c.f = f;
    unsigned int r = c.u + 0x7fffu + ((c.u >> 16) & 1u);
    return (short)(r >> 16);
}
// split fp32 -> bf16 hi + bf16 lo (a ~= hi + lo, rel err ~2^-16)
__device__ __forceinline__ void split_bf16(float x, short& hi, short& lo) {
    short h = f2bf(x);
    hi = h;
    lo = f2bf(x - bf2f(h));
}

// 16-lane (DPP row) all-reduce sum: quad_perm xor1, xor2, row_ror:4, row_ror:8.
__device__ __forceinline__ float row16_allreduce(float x) {
    union fi { float f; int i; };
    fi a, b;
    a.f = x;
    b.i = __builtin_amdgcn_update_dpp(0, a.i, 0xB1,  0xF, 0xF, true); a.f += b.f; // xor1
    b.i = __builtin_amdgcn_update_dpp(0, a.i, 0x4E,  0xF, 0xF, true); a.f += b.f; // xor2
    b.i = __builtin_amdgcn_update_dpp(0, a.i, 0x124, 0xF, 0xF, true); a.f += b.f; // ror4
    b.i = __builtin_amdgcn_update_dpp(0, a.i, 0x128, 0xF, 0xF, true); a.f += b.f; // ror8
    return a.f;
}

// W[K][N] fp32 row-major -> Wt[N][K]
__global__ __launch_bounds__(256) void transpose_k(const float* __restrict__ W,
                                                   float* __restrict__ Wt,
                                                   int K, int N) {
    int idx = blockIdx.x * 256 + threadIdx.x;
    if (idx >= N * K) return;
    int n = idx / K;
    int k = idx - n * K;
    Wt[idx] = W[k * N + n];
}

// C = A[M,K] @ Bt[N,K]^T. A fp32 or fp16, Bt fp32. Split-bf16 3-term MFMA, fp32 acc.
// MODE 0: fp32 out at row*N+col (+ optional fp32 bias)
// MODE 1: fp16 out at row*2048 + (col>>6)*128 + (col&63)   (dpfp staging layout)
template <typename AT, int MODE>
__global__ __launch_bounds__(256) void gemm_bt(const AT* __restrict__ A,
                                               const float* __restrict__ Bt,
                                               void* __restrict__ Cout,
                                               const float* __restrict__ bias,
                                               int N, int K) {
    __shared__ __align__(16) short As_h[64][40], As_l[64][40];
    __shared__ __align__(16) short Bs_h[64][40], Bs_l[64][40];
    const int tid  = threadIdx.x;
    const int wave = tid >> 6, lane = tid & 63;
    const int row0 = blockIdx.x * 64, col0 = blockIdx.y * 64;
    const int lr = tid >> 2, lc = (tid & 3) * 8;   // staging: 64 rows x 4 groups of 8
    const AT*    Ap = A  + (size_t)(row0 + lr) * K + lc;
    const float* Bp = Bt + (size_t)(col0 + lr) * K + lc;
    const int am = wave * 16 + (lane & 15);        // A-frag row
    const int ak = (lane >> 4) * 8;                // k-slice start
    floatx4 acc[4];
    #pragma unroll
    for (int t = 0; t < 4; ++t) acc[t] = (floatx4){0.f, 0.f, 0.f, 0.f};

    for (int k0 = 0; k0 < K; k0 += 32) {
        float av[8], bv[8];
        if constexpr (sizeof(AT) == 4) {
            floatx4 a0 = *(const floatx4*)(Ap + k0);
            floatx4 a1 = *(const floatx4*)(Ap + k0 + 4);
            #pragma unroll
            for (int j = 0; j < 4; ++j) { av[j] = a0[j]; av[4 + j] = a1[j]; }
        } else {
            half8 a = *(const half8*)(Ap + k0);
            #pragma unroll
            for (int j = 0; j < 8; ++j) av[j] = (float)a[j];
        }
        floatx4 b0 = *(const floatx4*)(Bp + k0);
        floatx4 b1 = *(const floatx4*)(Bp + k0 + 4);
        #pragma unroll
        for (int j = 0; j < 4; ++j) { bv[j] = b0[j]; bv[4 + j] = b1[j]; }

        short8 ah, al, bh, bl;
        #pragma unroll
        for (int j = 0; j < 8; ++j) {
            short h, l;
            split_bf16(av[j], h, l); ah[j] = h; al[j] = l;
            split_bf16(bv[j], h, l); bh[j] = h; bl[j] = l;
        }
        *(short8*)&As_h[lr][lc] = ah;
        *(short8*)&As_l[lr][lc] = al;
        *(short8*)&Bs_h[lr][lc] = bh;
        *(short8*)&Bs_l[lr][lc] = bl;
        __syncthreads();
        short8 afh = *(const short8*)&As_h[am][ak];
        short8 afl = *(const short8*)&As_l[am][ak];
        #pragma unroll
        for (int t = 0; t < 4; ++t) {
            short8 bfh = *(const short8*)&Bs_h[t * 16 + (lane & 15)][ak];
            short8 bfl = *(const short8*)&Bs_l[t * 16 + (lane & 15)][ak];
            acc[t] = __builtin_amdgcn_mfma_f32_16x16x32_bf16(afh, bfh, acc[t], 0, 0, 0);
            acc[t] = __builtin_amdgcn_mfma_f32_16x16x32_bf16(afh, bfl, acc[t], 0, 0, 0);
            acc[t] = __builtin_amdgcn_mfma_f32_16x16x32_bf16(afl, bfh, acc[t], 0, 0, 0);
        }
        __syncthreads();
    }
    // C/D layout (verified m89/m91): col = lane&15, row = (lane>>4)*4 + reg
    const int crow = row0 + wave * 16 + (lane >> 4) * 4;
    const int ccol = lane & 15;
    #pragma unroll
    for (int t = 0; t < 4; ++t) {
        int col = col0 + t * 16 + ccol;
        #pragma unroll
        for (int r = 0; r < 4; ++r) {
            int row = crow + r;
            float v = acc[t][r];
            if (MODE == 0) {
                float b = bias ? bias[col] : 0.f;
                ((float*)Cout)[(size_t)row * N + col] = v + b;
            } else {
                ((half_t*)Cout)[(size_t)row * 2048 + (col >> 6) * 128 + (col & 63)] = (half_t)v;
            }
        }
    }
}

// beta = sigmoid(x @ Wb); one wave per row, Wbt fp32 [16][1024]
__global__ __launch_bounds__(256) void beta_kernel(const float* __restrict__ X,
                                                   const float* __restrict__ Wbt,
                                                   float* __restrict__ Beta) {
    int wid  = (blockIdx.x * 256 + threadIdx.x) >> 6;
    int lane = threadIdx.x & 63;
    if (wid >= NROWS) return;
    const float* xr = X + (size_t)wid * DIM + lane * 16;
    float xv[16];
    #pragma unroll
    for (int j = 0; j < 4; ++j) {
        floatx4 v = *(const floatx4*)(xr + j * 4);
        #pragma unroll
        for (int e = 0; e < 4; ++e) xv[j * 4 + e] = v[e];
    }
    #pragma unroll 1
    for (int h = 0; h < 16; ++h) {
        const float* wr = Wbt + h * DIM + lane * 16;
        float s = 0.f;
        #pragma unroll
        for (int j = 0; j < 4; ++j) {
            floatx4 v = *(const floatx4*)(wr + j * 4);
            #pragma unroll
            for (int e = 0; e < 4; ++e) s = fmaf(xv[j * 4 + e], v[e], s);
        }
        #pragma unroll
        for (int off = 32; off; off >>= 1) s += __shfl_xor(s, off);
        if (lane == 0) Beta[wid * 16 + h] = 1.f / (1.f + __expf(-s));
    }
}

// In-place DPFP on fp16 spans of 128 (first 64 hold raw p, written by gemm MODE 1).
__global__ __launch_bounds__(256) void dpfp_h(half_t* __restrict__ P) {
    int gw   = (blockIdx.x * 256 + threadIdx.x) >> 6;
    int lane = threadIdx.x & 63;
    half_t* base = P + (size_t)gw * 128;
    float p  = (float)base[lane];
    float pm = __shfl(p, (lane + 63) & 63);           // p[lane-1], lane0 gets p[63]
    float rp  = fmaxf(p, 0.f),  rn  = fmaxf(-p, 0.f);
    float rpm = fmaxf(pm, 0.f), rnm = fmaxf(-pm, 0.f);
    float aprev = (lane == 0) ? rnm : rpm;            // xc[(lane-1)%128]
    float bprev = (lane == 0) ? rpm : rnm;            // xc[lane+63]
    float phi_a = rp * aprev;                         // phi[lane]
    float phi_b = rn * bprev;                         // phi[lane+64]
    float s = phi_a + phi_b;
    #pragma unroll
    for (int off = 32; off; off >>= 1) s += __shfl_xor(s, off);
    float inv = 1.f / (s + 1e-6f);
    base[lane]      = (half_t)(phi_a * inv);
    base[64 + lane] = (half_t)(phi_b * inv);
}

// Sequential fast-weight scan with LDS chunk double-buffering.
//   w <- w + beta*(v - w.k)*k ; y = w.q
// Block = one (b,h) x 16 state rows; 16 lanes/row x 8 fp32 state each.
// Chunks of 32 steps staged fp32 in LDS; global loads for chunk n+1 issued
// before chunk n's compute so the vmcnt drain lands ~4500 cyc after issue.
__global__ __launch_bounds__(256, 1) void scan_kernel(const half_t* __restrict__ PhiK,
                                                      const half_t* __restrict__ PhiQ,
                                                      const float* __restrict__ V,
                                                      const float* __restrict__ Beta,
                                                      half_t* __restrict__ Y) {
    __shared__ float Ks[2][CHUNK][128];   // 32 KB
    __shared__ float Qs[2][CHUNK][128];   // 32 KB
    __shared__ float Vs[2][CHUNK][16];    //  4 KB
    __shared__ float Bs[2][CHUNK];        // 256 B

    const int bh = blockIdx.x >> 2;     // 0..63
    const int rc = blockIdx.x & 3;      // row chunk
    const int b = bh >> 4, h = bh & 15;
    const int tid = threadIdx.x;
    const int row_l = tid >> 4;         // 0..15
    const int tc = tid & 15;            // column group (8 floats)
    const int vrow = rc * 16 + row_l;   // 0..63

    const half_t* kg = PhiK + h * 128;
    const half_t* qg = PhiQ + h * 128;
    const float*  vg = V + h * 64 + rc * 16;
    const float*  bg = Beta + h;
    half_t* ybase = Y + h * 64 + vrow;

    // ---- stage chunk 0 directly ----
    {
        #pragma unroll
        for (int rpt = 0; rpt < 2; ++rpt) {
            int i = rpt * 256 + tid;              // 0..511
            int st = i >> 4, seg = i & 15, row = i & 15;
            size_t r = (size_t)(st * BATCH + b);
            half8 kv = *(const half8*)(kg + r * 2048 + seg * 8);
            half8 qv = *(const half8*)(qg + r * 2048 + seg * 8);
            floatx4 klo, khi, qlo, qhi;
            #pragma unroll
            for (int j = 0; j < 4; ++j) {
                klo[j] = (float)kv[j]; khi[j] = (float)kv[4 + j];
                qlo[j] = (float)qv[j]; qhi[j] = (float)qv[4 + j];
            }
            *(floatx4*)&Ks[0][st][seg * 8]     = klo;
            *(floatx4*)&Ks[0][st][seg * 8 + 4] = khi;
            *(floatx4*)&Qs[0][st][seg * 8]     = qlo;
            *(floatx4*)&Qs[0][st][seg * 8 + 4] = qhi;
            Vs[0][st][row] = vg[r * 1024 + row];
        }
        if (tid < CHUNK) {
            size_t r = (size_t)(tid * BATCH + b);
            Bs[0][tid] = bg[r * 16];
        }
    }
    __syncthreads();

    float w[8];
    #pragma unroll
    for (int j = 0; j < 8; ++j) w[j] = 0.f;

    for (int c = 0; c < NCHUNK; ++c) {
        const int bufi = c & 1;
        const bool more = (c + 1 < NCHUNK);
        // ---- issue global loads for chunk c+1 (held in regs until after compute) ----
        half8 pk[2], pq[2];
        float pv[2], pb = 0.f;
        if (more) {
            #pragma unroll
            for (int rpt = 0; rpt < 2; ++rpt) {
                int i = rpt * 256 + tid;
                int st = i >> 4, seg = i & 15, row = i & 15;
                size_t r = (size_t)(((c + 1) * CHUNK + st) * BATCH + b);
                pk[rpt] = *(const half8*)(kg + r * 2048 + seg * 8);
                pq[rpt] = *(const half8*)(qg + r * 2048 + seg * 8);
                pv[rpt] = vg[r * 1024 + row];
            }
            if (tid < CHUNK) {
                size_t r = (size_t)(((c + 1) * CHUNK + tid) * BATCH + b);
                pb = bg[r * 16];
            }
        }
        // ---- compute chunk c from LDS, 1-step register prefetch ----
        float Ak[8], Aq[8], Av, Ab;
        float Bk[8], Bq[8], Bv, Bb;
        {
            floatx4 k0 = *(const floatx4*)&Ks[bufi][0][tc * 8];
            floatx4 k1 = *(const floatx4*)&Ks[bufi][0][tc * 8 + 4];
            floatx4 q0 = *(const floatx4*)&Qs[bufi][0][tc * 8];
            floatx4 q1 = *(const floatx4*)&Qs[bufi][0][tc * 8 + 4];
            #pragma unroll
            for (int j = 0; j < 4; ++j) {
                Ak[j] = k0[j]; Ak[4 + j] = k1[j];
                Aq[j] = q0[j]; Aq[4 + j] = q1[j];
            }
            Av = Vs[bufi][0][row_l];
            Ab = Bs[bufi][0];
        }
        #pragma unroll 1
        for (int u = 0; u < CHUNK; u += 2) {
            // prefetch u+1
            {
                floatx4 k0 = *(const floatx4*)&Ks[bufi][u + 1][tc * 8];
                floatx4 k1 = *(const floatx4*)&Ks[bufi][u + 1][tc * 8 + 4];
                floatx4 q0 = *(const floatx4*)&Qs[bufi][u + 1][tc * 8];
                floatx4 q1 = *(const floatx4*)&Qs[bufi][u + 1][tc * 8 + 4];
                #pragma unroll
                for (int j = 0; j < 4; ++j) {
                    Bk[j] = k0[j]; Bk[4 + j] = k1[j];
                    Bq[j] = q0[j]; Bq[4 + j] = q1[j];
                }
                Bv = Vs[bufi][u + 1][row_l];
                Bb = Bs[bufi][u + 1];
            }
            // step u (A regs)
            {
                float d0 = w[0] * Ak[0], d1 = w[1] * Ak[1];
                d0 = fmaf(w[2], Ak[2], d0); d1 = fmaf(w[3], Ak[3], d1);
                d0 = fmaf(w[4], Ak[4], d0); d1 = fmaf(w[5], Ak[5], d1);
                d0 = fmaf(w[6], Ak[6], d0); d1 = fmaf(w[7], Ak[7], d1);
                float d = row16_allreduce(d0 + d1);
                float coef = Ab * (Av - d);
                #pragma unroll
                for (int j = 0; j < 8; ++j) w[j] = fmaf(coef, Ak[j], w[j]);
                float y0 = w[0] * Aq[0], y1 = w[1] * Aq[1];
                y0 = fmaf(w[2], Aq[2], y0); y1 = fmaf(w[3], Aq[3], y1);
                y0 = fmaf(w[4], Aq[4], y0); y1 = fmaf(w[5], Aq[5], y1);
                y0 = fmaf(w[6], Aq[6], y0); y1 = fmaf(w[7], Aq[7], y1);
                float y = row16_allreduce(y0 + y1);
                if (tc == 0)
                    ybase[(size_t)((c * CHUNK + u) * BATCH + b) * 1024] = (half_t)y;
            }
            // prefetch u+2
            if (u + 2 < CHUNK) {
                floatx4 k0 = *(const floatx4*)&Ks[bufi][u + 2][tc * 8];
                floatx4 k1 = *(const floatx4*)&Ks[bufi][u + 2][tc * 8 + 4];
                floatx4 q0 = *(const floatx4*)&Qs[bufi][u + 2][tc * 8];
                floatx4 q1 = *(const floatx4*)&Qs[bufi][u + 2][tc * 8 + 4];
                #pragma unroll
                for (int j = 0; j < 4; ++j) {
                    Ak[j] = k0[j]; Ak[4 + j] = k1[j];
                    Aq[j] = q0[j]; Aq[4 + j] = q1[j];
                }
                Av = Vs[bufi][u + 2][row_l];
                Ab = Bs[bufi][u + 2];
            }
            // step u+1 (B regs)
            {
                float d0 = w[0] * Bk[0], d1 = w[1] * Bk[1];
                d0 = fmaf(w[2], Bk[2], d0); d1 = fmaf(w[3], Bk[3], d1);
                d0 = fmaf(w[4], Bk[4], d0); d1 = fmaf(w[5], Bk[5], d1);
                d0 = fmaf(w[6], Bk[6], d0); d1 = fmaf(w[7], Bk[7], d1);
                float d = row16_allreduce(d0 + d1);
                float coef = Bb * (Bv - d);
                #pragma unroll
                for (int j = 0; j < 8; ++j) w[j] = fmaf(coef, Bk[j], w[j]);
                float y0 = w[0] * Bq[0], y1 = w[1] * Bq[1];
                y0 = fmaf(w[2], Bq[2], y0); y1 = fmaf(w[3], Bq[3], y1);
                y0 = fmaf(w[4], Bq[4], y0); y1 = fmaf(w[5], Bq[5], y1);
                y0 = fmaf(w[6], Bq[6], y0); y1 = fmaf(w[7], Bq[7], y1);
                float y = row16_allreduce(y0 + y1);
                if (tc == 0)
                    ybase[(size_t)((c * CHUNK + u + 1) * BATCH + b) * 1024] = (half_t)y;
            }
        }
        // ---- write staged chunk c+1 into the other buffer ----
        if (more) {
            const int bufn = bufi ^ 1;
            #pragma unroll
            for (int rpt = 0; rpt < 2; ++rpt) {
                int i = rpt * 256 + tid;
                int st = i >> 4, seg = i & 15, row = i & 15;
                floatx4 klo, khi, qlo, qhi;
                #pragma unroll
                for (int j = 0; j < 4; ++j) {
                    klo[j] = (float)pk[rpt][j]; khi[j] = (float)pk[rpt][4 + j];
                    qlo[j] = (float)pq[rpt][j]; qhi[j] = (float)pq[rpt][4 + j];
                }
                *(floatx4*)&Ks[bufn][st][seg * 8]     = klo;
                *(floatx4*)&Ks[bufn][st][seg * 8 + 4] = khi;
                *(floatx4*)&Qs[bufn][st][seg * 8]     = qlo;
                *(floatx4*)&Qs[bufn][st][seg * 8 + 4] = qhi;
                Vs[bufn][st][row] = pv[rpt];
            }
            if (tid < CHUNK) Bs[bufn][tid] = pb;
        }
        __syncthreads();
    }
}

extern "C" void kernel_launch(void* const* d_in, const int* in_sizes, int n_in,
                              void* d_out, int out_size, void* d_ws, size_t ws_size,
                              hipStream_t stream) {
    const float* x  = (const float*)d_in[0];
    const float* Wq = (const float*)d_in[1];
    const float* Wk = (const float*)d_in[2];
    const float* Wv = (const float*)d_in[3];
    const float* Wb = (const float*)d_in[4];
    const float* Wo = (const float*)d_in[5];
    const float* bo = (const float*)d_in[6];

    char* ws = (char*)d_ws;
    size_t off = 0;
    auto alloc = [&](size_t bytes) -> void* {
        void* p = ws + off;
        off += (bytes + 255) & ~(size_t)255;
        return p;
    };
    half_t* PhiQ = (half_t*)alloc((size_t)NROWS * 2048 * 2);  // 64 MB
    half_t* PhiK = (half_t*)alloc((size_t)NROWS * 2048 * 2);  // 64 MB
    half_t* Yb   = (half_t*)alloc((size_t)NROWS * 1024 * 2);  // 32 MB
    float*  Beta = (float*)alloc((size_t)NROWS * 16 * 4);     //  1 MB
    float*  Wqt  = (float*)alloc((size_t)1024 * 1024 * 4);    //  4 MB
    float*  Wkt  = (float*)alloc((size_t)1024 * 1024 * 4);
    float*  Wvt  = (float*)alloc((size_t)1024 * 1024 * 4);
    float*  Wot  = (float*)alloc((size_t)1024 * 1024 * 4);
    float*  Wbt  = (float*)alloc((size_t)16 * 1024 * 4);
    float*  Vb   = (float*)d_out;  // V staged in d_out (fp32, dead before final GEMM)

    transpose_k<<<4096, 256, 0, stream>>>(Wq, Wqt, 1024, 1024);
    transpose_k<<<4096, 256, 0, stream>>>(Wk, Wkt, 1024, 1024);
    transpose_k<<<4096, 256, 0, stream>>>(Wv, Wvt, 1024, 1024);
    transpose_k<<<4096, 256, 0, stream>>>(Wo, Wot, 1024, 1024);
    transpose_k<<<64,   256, 0, stream>>>(Wb, Wbt, 1024, 16);

    dim3 ggrid(NROWS / 64, DIM / 64);
    const int dgrid = (NROWS * 16) / 4;
    gemm_bt<float, 1><<<ggrid, 256, 0, stream>>>(x, Wqt, PhiQ, nullptr, DIM, DIM);
    dpfp_h<<<dgrid, 256, 0, stream>>>(PhiQ);
    gemm_bt<float, 1><<<ggrid, 256, 0, stream>>>(x, Wkt, PhiK, nullptr, DIM, DIM);
    dpfp_h<<<dgrid, 256, 0, stream>>>(PhiK);
    gemm_bt<float, 0><<<ggrid, 256, 0, stream>>>(x, Wvt, Vb, nullptr, DIM, DIM);
    beta_kernel<<<NROWS / 4, 256, 0, stream>>>(x, Wbt, Beta);
    scan_kernel<<<256, 256, 0, stream>>>(PhiK, PhiQ, Vb, Beta, Yb);
    gemm_bt<half_t, 0><<<ggrid, 256, 0, stream>>>(Yb, Wot, d_out, bo, DIM, DIM);
}